// Round 2
// baseline (2765.733 us; speedup 1.0000x reference)
//
#include <hip/hip_runtime.h>
#include <hip/hip_bf16.h>

#define SEQ   320
#define HDIM  400
#define GATES 1600
#define NCOL  3200
#define GD    50    // workgroups per direction in the recurrent kernel
#define JPW   8     // h-rows owned per workgroup (400/50)

// ---------------------------------------------------------------- embeddings
__global__ __launch_bounds__(256) void embed_kernel(
    const int* __restrict__ words, const int* __restrict__ tags,
    const float* __restrict__ wemb, const float* __restrict__ temb,
    float* __restrict__ x)
{
    int i = blockIdx.x * 256 + threadIdx.x;
    if (i >= SEQ * 400) return;
    int t = i / 400, c = i % 400;
    x[i] = (c < 300) ? wemb[(size_t)words[t] * 300 + c]
                     : temb[(size_t)tags[t] * 100 + (c - 300)];
}

// ---------------------------------------------------------------- bias prep
__global__ __launch_bounds__(256) void bias_kernel(
    const float* __restrict__ bihl0,  const float* __restrict__ bhhl0,
    const float* __restrict__ bihl0r, const float* __restrict__ bhhl0r,
    const float* __restrict__ bihl1,  const float* __restrict__ bhhl1,
    const float* __restrict__ bihl1r, const float* __restrict__ bhhl1r,
    const float* __restrict__ mlpb1,
    float* __restrict__ bL0, float* __restrict__ bL1, float* __restrict__ bAB)
{
    int g = blockIdx.x * 256 + threadIdx.x;
    if (g >= NCOL) return;
    if (g < GATES) {
        bL0[g] = bihl0[g] + bhhl0[g];
        bL1[g] = bihl1[g] + bhhl1[g];
        bAB[g] = mlpb1[g];
    } else {
        int q = g - GATES;
        bL0[g] = bihl0r[q] + bhhl0r[q];
        bL1[g] = bihl1r[q] + bhhl1r[q];
        bAB[g] = 0.f;
    }
}

// ---------------------------------------------------------------- tiled SGEMM
__global__ __launch_bounds__(256) void gemm_bias(
    const float* __restrict__ A, int lda, int K,
    const float* __restrict__ B0, const float* __restrict__ B1, int ldb,
    const float* __restrict__ bias, float* __restrict__ C)
{
    __shared__ float As[16][68];   // +4 pad: k-major, conflict-free
    __shared__ float Bs[16][68];
    const int m0 = blockIdx.y * 64, n0 = blockIdx.x * 64;
    const int tid = threadIdx.x, tx = tid & 15, ty = tid >> 4;
    float acc[4][4] = {};
    for (int k0 = 0; k0 < K; k0 += 16) {
        for (int i = tid; i < 1024; i += 256) {
            int r = i >> 4, c = i & 15;
            As[c][r] = A[(size_t)(m0 + r) * lda + k0 + c];
            int n = n0 + r;
            const float* brow = (n < GATES) ? (B0 + (size_t)n * ldb)
                                            : (B1 + (size_t)(n - GATES) * ldb);
            Bs[c][r] = brow[k0 + c];
        }
        __syncthreads();
#pragma unroll
        for (int kk = 0; kk < 16; ++kk) {
            float4 a4 = *(const float4*)&As[kk][ty * 4];
            float4 b4 = *(const float4*)&Bs[kk][tx * 4];
            float av[4] = {a4.x, a4.y, a4.z, a4.w};
            float bv[4] = {b4.x, b4.y, b4.z, b4.w};
#pragma unroll
            for (int i2 = 0; i2 < 4; ++i2)
#pragma unroll
                for (int j2 = 0; j2 < 4; ++j2)
                    acc[i2][j2] += av[i2] * bv[j2];
        }
        __syncthreads();
    }
#pragma unroll
    for (int i2 = 0; i2 < 4; ++i2) {
        int m = m0 + ty * 4 + i2;
#pragma unroll
        for (int j2 = 0; j2 < 4; ++j2) {
            int n = n0 + tx * 4 + j2;
            C[(size_t)m * NCOL + n] = acc[i2][j2] + bias[n];
        }
    }
}

// ---------------------------------------------------------------- recurrence
// Persistent spin-sync BiLSTM layer. 2 directions x GD workgroups. Each WG
// owns JPW h-rows; its 32 w_hh rows stay LDS-resident for all 320 steps.
// h history lives in `out` (SEQ x 800, fwd cols 0..399, bwd 400..799),
// pre-filled with 0xFFFFFFFF sentinel: the data itself is the ready flag.
//
// Critical-path design (R1): gates prefetched at loop top (independent of h,
// overlaps the poll); h polled by 100 threads as 16B chunks (2x u64 agent
// loads issued together); h/g double-buffered in LDS -> ONE barrier per step.
__global__ __launch_bounds__(256) void lstm_layer(
    const float* __restrict__ gates,   // SEQ x 3200 (x@W_ih^T + biases)
    const float* __restrict__ whh_f, const float* __restrict__ whh_b,
    const float* __restrict__ h0f, const float* __restrict__ h0b,
    const float* __restrict__ c0f, const float* __restrict__ c0b,
    float* out)
{
    __shared__ float w_lds[32 * 400];   // 51.2 KB
    __shared__ float h_lds[2][400];
    __shared__ float g_lds[2][32];
    const int tid = threadIdx.x;
    const int dir = blockIdx.x / GD;
    const int wg  = blockIdx.x % GD;
    const int j0  = wg * JPW;
    const float* whh = dir ? whh_b : whh_f;
    const float* h0d = dir ? h0b : h0f;
    const float* c0d = dir ? c0b : c0f;

    // stage w_hh slice, float4-wide: local row (jl*4+gate) <-> global row gate*400+(j0+jl)
    for (int lr = 0; lr < 32; ++lr) {
        int grow = (lr & 3) * 400 + j0 + (lr >> 2);
        const float4* src4 = (const float4*)(whh + (size_t)grow * 400);
        float4* dst4 = (float4*)(w_lds + lr * 400);
        for (int k = tid; k < 100; k += 256) dst4[k] = src4[k];
    }

    const int j_local = tid >> 5;   // 8 groups of 32 lanes, one h-row each
    const int sub     = tid & 31;
    const int j       = j0 + j_local;
    float c_prev = (sub == 0) ? c0d[j] : 0.f;

    for (int s = 0; s < 320; ++s) {
        const int row = dir ? (319 - s) : s;
        const int buf = s & 1;

        // gate prefetch (independent of h_prev -> overlaps the poll)
        float gval = 0.f;
        if (tid < 32)
            gval = gates[(size_t)row * NCOL + dir * GATES + (tid & 3) * 400 +
                         j0 + (tid >> 2)];

        if (s == 0) {
            if (tid < 100)
                ((float4*)h_lds[0])[tid] = ((const float4*)h0d)[tid];
        } else if (tid < 100) {
            const int rp = dir ? (row + 1) : (row - 1);
            const unsigned long long* src =
                (const unsigned long long*)(out + (size_t)rp * 800 + dir * 400) +
                tid * 2;
            unsigned long long a = __hip_atomic_load(src, __ATOMIC_RELAXED,
                                                     __HIP_MEMORY_SCOPE_AGENT);
            unsigned long long b = __hip_atomic_load(src + 1, __ATOMIC_RELAXED,
                                                     __HIP_MEMORY_SCOPE_AGENT);
            while ((unsigned)a == 0xFFFFFFFFu || (unsigned)(a >> 32) == 0xFFFFFFFFu)
                a = __hip_atomic_load(src, __ATOMIC_RELAXED,
                                      __HIP_MEMORY_SCOPE_AGENT);
            while ((unsigned)b == 0xFFFFFFFFu || (unsigned)(b >> 32) == 0xFFFFFFFFu)
                b = __hip_atomic_load(src + 1, __ATOMIC_RELAXED,
                                      __HIP_MEMORY_SCOPE_AGENT);
            float* dst = &h_lds[buf][tid * 4];
            dst[0] = __uint_as_float((unsigned)a);
            dst[1] = __uint_as_float((unsigned)(a >> 32));
            dst[2] = __uint_as_float((unsigned)b);
            dst[3] = __uint_as_float((unsigned)(b >> 32));
        }
        if (tid < 32) g_lds[buf][tid] = gval;
        __syncthreads();   // the ONLY barrier per step (h/g double-buffered)

        float p[4];
        const float4* h4 = (const float4*)h_lds[buf];
#pragma unroll
        for (int gate = 0; gate < 4; ++gate) {
            const float4* w4 = (const float4*)&w_lds[(j_local * 4 + gate) * 400];
            float acc = 0.f;
            for (int k4 = sub; k4 < 100; k4 += 32) {
                float4 w = w4[k4], h = h4[k4];
                acc += w.x * h.x + w.y * h.y + w.z * h.z + w.w * h.w;
            }
            p[gate] = acc;
        }
#pragma unroll
        for (int m = 16; m >= 1; m >>= 1) {  // reduce within each 32-lane half
            p[0] += __shfl_xor(p[0], m, 64);
            p[1] += __shfl_xor(p[1], m, 64);
            p[2] += __shfl_xor(p[2], m, 64);
            p[3] += __shfl_xor(p[3], m, 64);
        }
        if (sub == 0) {
            const float* gl = g_lds[buf] + j_local * 4;
            float gi = gl[0] + p[0];
            float gf = gl[1] + p[1];
            float gg = gl[2] + p[2];
            float go = gl[3] + p[3];
            float iv = 1.f / (1.f + __expf(-gi));
            float fv = 1.f / (1.f + __expf(-gf));
            float ov = 1.f / (1.f + __expf(-go));
            c_prev = fv * c_prev + iv * tanhf(gg);
            float hv = ov * tanhf(c_prev);
            __hip_atomic_store((unsigned*)(out + (size_t)row * 800 + dir * 400 + j),
                               __float_as_uint(hv), __ATOMIC_RELAXED,
                               __HIP_MEMORY_SCOPE_AGENT);
        }
        // no trailing barrier: next step writes the other h/g buffer
    }
}

// ---------------------------------------------------------------- fused scorer
__global__ __launch_bounds__(256) void scores_kernel(
    const float* __restrict__ ab, const float* __restrict__ w2,
    const float* __restrict__ b2, float* __restrict__ out)
{
    __shared__ float a_s[16 * 132];
    __shared__ float b_s[16 * 132];
    __shared__ float w_s[128];
    const int tx = threadIdx.x, ty = threadIdx.y;
    const int tid = ty * 16 + tx;
    const int n0 = blockIdx.y * 16, d0 = blockIdx.x * 16;
    float acc = 0.f;
    for (int kc = 0; kc < 1600; kc += 128) {
        for (int i = tid; i < 16 * 128; i += 256) {
            int r = i >> 7, c = i & 127;
            a_s[r * 132 + c] = ab[(size_t)(n0 + r) * NCOL + kc + c];
            b_s[r * 132 + c] = ab[(size_t)(d0 + r) * NCOL + 1600 + kc + c];
        }
        if (tid < 128) w_s[tid] = w2[kc + tid];
        __syncthreads();
#pragma unroll
        for (int k = 0; k < 128; k += 4) {
            float4 av = *(const float4*)&a_s[ty * 132 + k];
            float4 bv = *(const float4*)&b_s[tx * 132 + k];
            float4 wv = *(const float4*)&w_s[k];
            acc += fmaxf(av.x + bv.x, 0.f) * wv.x;
            acc += fmaxf(av.y + bv.y, 0.f) * wv.y;
            acc += fmaxf(av.z + bv.z, 0.f) * wv.z;
            acc += fmaxf(av.w + bv.w, 0.f) * wv.w;
        }
        __syncthreads();
    }
    int n = n0 + ty, d = d0 + tx;
    out[(size_t)(n + 1) * 321 + (d + 1)] = (n == d) ? 0.f : (acc + b2[0]);
}

__global__ void border_kernel(float* out) {
    int i = blockIdx.x * 256 + threadIdx.x;
    if (i < 321) {
        out[i]               = (i == 0) ? 1.f : 0.f;  // row 0
        out[(size_t)i * 321] = (i == 0) ? 1.f : 0.f;  // col 0
    }
}

// ---------------------------------------------------------------- launcher
extern "C" void kernel_launch(void* const* d_in, const int* in_sizes, int n_in,
                              void* d_out, int out_size, void* d_ws, size_t ws_size,
                              hipStream_t stream)
{
    const int*   words    = (const int*)d_in[0];
    const int*   tags     = (const int*)d_in[1];
    const float* wemb     = (const float*)d_in[3];
    const float* temb     = (const float*)d_in[4];
    const float* h0       = (const float*)d_in[5];
    const float* c0       = (const float*)d_in[6];
    const float* w_ih_l0  = (const float*)d_in[7];
    const float* w_hh_l0  = (const float*)d_in[8];
    const float* b_ih_l0  = (const float*)d_in[9];
    const float* b_hh_l0  = (const float*)d_in[10];
    const float* w_ih_l0r = (const float*)d_in[11];
    const float* w_hh_l0r = (const float*)d_in[12];
    const float* b_ih_l0r = (const float*)d_in[13];
    const float* b_hh_l0r = (const float*)d_in[14];
    const float* w_ih_l1  = (const float*)d_in[15];
    const float* w_hh_l1  = (const float*)d_in[16];
    const float* b_ih_l1  = (const float*)d_in[17];
    const float* b_hh_l1  = (const float*)d_in[18];
    const float* w_ih_l1r = (const float*)d_in[19];
    const float* w_hh_l1r = (const float*)d_in[20];
    const float* b_ih_l1r = (const float*)d_in[21];
    const float* b_hh_l1r = (const float*)d_in[22];
    const float* mlp_w1   = (const float*)d_in[23];
    const float* mlp_b1   = (const float*)d_in[24];
    const float* mlp_w2   = (const float*)d_in[25];
    const float* mlp_b2   = (const float*)d_in[26];
    float* out = (float*)d_out;

    float* ws     = (float*)d_ws;
    float* x      = ws;                 // 320*400   = 128000
    float* out0   = ws + 128000;        // 320*800   = 256000
    float* out1   = ws + 384000;        // 320*800   = 256000
    float* gates  = ws + 640000;        // 320*3200  = 1024000 (reused: g0, g1, ab)
    float* biasL0 = ws + 1664000;       // 3200
    float* biasL1 = ws + 1667200;       // 3200
    float* biasAB = ws + 1670400;       // 3200

    // sentinel-fill the recurrent h-history buffers (data doubles as ready flag)
    hipMemsetAsync(out0, 0xFF, (size_t)2 * 256000 * 4, stream);

    embed_kernel<<<500, 256, 0, stream>>>(words, tags, wemb, temb, x);
    bias_kernel<<<13, 256, 0, stream>>>(b_ih_l0, b_hh_l0, b_ih_l0r, b_hh_l0r,
                                        b_ih_l1, b_hh_l1, b_ih_l1r, b_hh_l1r,
                                        mlp_b1, biasL0, biasL1, biasAB);

    dim3 gdim(50, 5);
    gemm_bias<<<gdim, 256, 0, stream>>>(x, 400, 400, w_ih_l0, w_ih_l0r, 400,
                                        biasL0, gates);
    lstm_layer<<<2 * GD, 256, 0, stream>>>(gates, w_hh_l0, w_hh_l0r,
                                           h0, h0 + 400, c0, c0 + 400, out0);
    gemm_bias<<<gdim, 256, 0, stream>>>(out0, 800, 800, w_ih_l1, w_ih_l1r, 800,
                                        biasL1, gates);
    lstm_layer<<<2 * GD, 256, 0, stream>>>(gates, w_hh_l1, w_hh_l1r,
                                           h0 + 800, h0 + 1200, c0 + 800, c0 + 1200,
                                           out1);
    gemm_bias<<<gdim, 256, 0, stream>>>(out1, 800, 800, mlp_w1, mlp_w1 + 800, 1600,
                                        biasAB, gates);

    dim3 sgrid(20, 20), sblock(16, 16);
    scores_kernel<<<sgrid, sblock, 0, stream>>>(gates, mlp_w2, mlp_b2, out);
    border_kernel<<<2, 256, 0, stream>>>(out);
}

// Round 3
// 2358.002 us; speedup vs baseline: 1.1729x; 1.1729x over previous
//
#include <hip/hip_runtime.h>
#include <hip/hip_bf16.h>

#define SEQ   320
#define HDIM  400
#define GATES 1600
#define NCOL  3200
#define GDW   8     // workgroups per direction in the recurrent kernel
#define RPW   50    // h-rows owned per workgroup (400/8)

// ---------------------------------------------------------------- embeddings
__global__ __launch_bounds__(256) void embed_kernel(
    const int* __restrict__ words, const int* __restrict__ tags,
    const float* __restrict__ wemb, const float* __restrict__ temb,
    float* __restrict__ x)
{
    int i = blockIdx.x * 256 + threadIdx.x;
    if (i >= SEQ * 400) return;
    int t = i / 400, c = i % 400;
    x[i] = (c < 300) ? wemb[(size_t)words[t] * 300 + c]
                     : temb[(size_t)tags[t] * 100 + (c - 300)];
}

// ---------------------------------------------------------------- bias prep
__global__ __launch_bounds__(256) void bias_kernel(
    const float* __restrict__ bihl0,  const float* __restrict__ bhhl0,
    const float* __restrict__ bihl0r, const float* __restrict__ bhhl0r,
    const float* __restrict__ bihl1,  const float* __restrict__ bhhl1,
    const float* __restrict__ bihl1r, const float* __restrict__ bhhl1r,
    const float* __restrict__ mlpb1,
    float* __restrict__ bL0, float* __restrict__ bL1, float* __restrict__ bAB)
{
    int g = blockIdx.x * 256 + threadIdx.x;
    if (g >= NCOL) return;
    if (g < GATES) {
        bL0[g] = bihl0[g] + bhhl0[g];
        bL1[g] = bihl1[g] + bhhl1[g];
        bAB[g] = mlpb1[g];
    } else {
        int q = g - GATES;
        bL0[g] = bihl0r[q] + bhhl0r[q];
        bL1[g] = bihl1r[q] + bhhl1r[q];
        bAB[g] = 0.f;
    }
}

// ---------------------------------------------------------------- tiled SGEMM
__global__ __launch_bounds__(256) void gemm_bias(
    const float* __restrict__ A, int lda, int K,
    const float* __restrict__ B0, const float* __restrict__ B1, int ldb,
    const float* __restrict__ bias, float* __restrict__ C)
{
    __shared__ float As[16][68];   // +4 pad: k-major, conflict-free
    __shared__ float Bs[16][68];
    const int m0 = blockIdx.y * 64, n0 = blockIdx.x * 64;
    const int tid = threadIdx.x, tx = tid & 15, ty = tid >> 4;
    float acc[4][4] = {};
    for (int k0 = 0; k0 < K; k0 += 16) {
        for (int i = tid; i < 1024; i += 256) {
            int r = i >> 4, c = i & 15;
            As[c][r] = A[(size_t)(m0 + r) * lda + k0 + c];
            int n = n0 + r;
            const float* brow = (n < GATES) ? (B0 + (size_t)n * ldb)
                                            : (B1 + (size_t)(n - GATES) * ldb);
            Bs[c][r] = brow[k0 + c];
        }
        __syncthreads();
#pragma unroll
        for (int kk = 0; kk < 16; ++kk) {
            float4 a4 = *(const float4*)&As[kk][ty * 4];
            float4 b4 = *(const float4*)&Bs[kk][tx * 4];
            float av[4] = {a4.x, a4.y, a4.z, a4.w};
            float bv[4] = {b4.x, b4.y, b4.z, b4.w};
#pragma unroll
            for (int i2 = 0; i2 < 4; ++i2)
#pragma unroll
                for (int j2 = 0; j2 < 4; ++j2)
                    acc[i2][j2] += av[i2] * bv[j2];
        }
        __syncthreads();
    }
#pragma unroll
    for (int i2 = 0; i2 < 4; ++i2) {
        int m = m0 + ty * 4 + i2;
#pragma unroll
        for (int j2 = 0; j2 < 4; ++j2) {
            int n = n0 + tx * 4 + j2;
            C[(size_t)m * NCOL + n] = acc[i2][j2] + bias[n];
        }
    }
}

// ---------------------------------------------------------------- recurrence
// R3 redesign: sync domain shrunk 50 -> 8 WGs/direction. Each WG owns 50
// h-rows; W_hh slice lives in VGPRs (200 fp32/thread, wave=(gate,k-half),
// lane=row). h_prev broadcast-read from LDS (same-address float4 = free).
// h history in `out` pre-filled with 0xFFFFFFFF sentinel (data = ready flag);
// 4 redundant pollers per 16B chunk cut detection cadence.
__global__ __launch_bounds__(512, 2) void lstm_layer(
    const float* __restrict__ gates,   // SEQ x 3200 (x@W_ih^T + biases)
    const float* __restrict__ whh_f, const float* __restrict__ whh_b,
    const float* __restrict__ h0f, const float* __restrict__ h0b,
    const float* __restrict__ c0f, const float* __restrict__ c0b,
    float* out)
{
    __shared__ float h_lds[400];
    __shared__ float part[8][52];      // stride 52: distinct banks across w
    const int tid = threadIdx.x;
    const int dir = blockIdx.x >> 3;
    const int wg  = blockIdx.x & 7;
    const int j0  = wg * RPW;
    const float* whh = dir ? whh_b : whh_f;
    const float* h0d = dir ? h0b : h0f;
    const float* c0d = dir ? c0b : c0f;

    const int w    = tid >> 6;         // wave 0..7
    const int lane = tid & 63;
    const int g    = w & 3;            // gate
    const int kh   = w >> 2;           // k-half (0: k<200, 1: k>=200)
    const int jrow = j0 + (lane < 50 ? lane : 49);

    // ---- one-time: 200 W_hh weights per thread into registers
    float wr[200];
    {
        const float4* wp = (const float4*)(whh + (size_t)(g * 400 + jrow) * 400 + kh * 200);
#pragma unroll
        for (int k = 0; k < 50; ++k) {
            float4 t = wp[k];
            wr[4 * k + 0] = t.x; wr[4 * k + 1] = t.y;
            wr[4 * k + 2] = t.z; wr[4 * k + 3] = t.w;
        }
    }

    const int pc = tid % 100;          // poll chunk (16B)
    const int pr = tid / 100;          // poll replica; replicas 0..3 active
    float c_prev = (tid < RPW) ? c0d[j0 + tid] : 0.f;

    for (int s = 0; s < 320; ++s) {
        const int row = dir ? (319 - s) : s;

        // gate prefetch for activation threads (independent of h_prev)
        float gv0 = 0.f, gv1 = 0.f, gv2 = 0.f, gv3 = 0.f;
        if (tid < RPW) {
            const float* gx = gates + (size_t)row * NCOL + dir * GATES + j0 + tid;
            gv0 = gx[0]; gv1 = gx[400]; gv2 = gx[800]; gv3 = gx[1200];
        }

        if (s == 0) {
            if (tid < 100) ((float4*)h_lds)[tid] = ((const float4*)h0d)[tid];
        } else if (pr < 4) {
            const int rp = dir ? (row + 1) : (row - 1);
            const unsigned long long* src =
                (const unsigned long long*)(out + (size_t)rp * 800 + dir * 400) + pc * 2;
            unsigned long long a, b;
            for (;;) {
                a = __hip_atomic_load(src,     __ATOMIC_RELAXED, __HIP_MEMORY_SCOPE_AGENT);
                b = __hip_atomic_load(src + 1, __ATOMIC_RELAXED, __HIP_MEMORY_SCOPE_AGENT);
                if ((unsigned)a != 0xFFFFFFFFu && (unsigned)(a >> 32) != 0xFFFFFFFFu &&
                    (unsigned)b != 0xFFFFFFFFu && (unsigned)(b >> 32) != 0xFFFFFFFFu)
                    break;
            }
            float* dst = &h_lds[pc * 4];
            dst[0] = __uint_as_float((unsigned)a);
            dst[1] = __uint_as_float((unsigned)(a >> 32));
            dst[2] = __uint_as_float((unsigned)b);
            dst[3] = __uint_as_float((unsigned)(b >> 32));
        }
        __syncthreads();

        // partial dot over this wave's k-half; h broadcast from LDS
        {
            const float4* h4 = (const float4*)&h_lds[kh * 200];
            float a0 = 0.f, a1 = 0.f, a2 = 0.f, a3 = 0.f;
#pragma unroll
            for (int k = 0; k < 50; ++k) {
                float4 hv = h4[k];
                a0 += wr[4 * k + 0] * hv.x;
                a1 += wr[4 * k + 1] * hv.y;
                a2 += wr[4 * k + 2] * hv.z;
                a3 += wr[4 * k + 3] * hv.w;
            }
            if (lane < 50) part[w][lane] = (a0 + a1) + (a2 + a3);
        }
        __syncthreads();

        if (tid < RPW) {
            float gi = gv0 + part[0][tid] + part[4][tid];
            float gf = gv1 + part[1][tid] + part[5][tid];
            float gg = gv2 + part[2][tid] + part[6][tid];
            float go = gv3 + part[3][tid] + part[7][tid];
            float iv = 1.f / (1.f + __expf(-gi));
            float fv = 1.f / (1.f + __expf(-gf));
            float ov = 1.f / (1.f + __expf(-go));
            float tg = 1.f - 2.f / (1.f + __expf(2.f * gg));
            c_prev = fv * c_prev + iv * tg;
            float tc = 1.f - 2.f / (1.f + __expf(2.f * c_prev));
            float hv = ov * tc;
            __hip_atomic_store((unsigned*)(out + (size_t)row * 800 + dir * 400 + j0 + tid),
                               __float_as_uint(hv), __ATOMIC_RELAXED,
                               __HIP_MEMORY_SCOPE_AGENT);
        }
        // hazards: h_lds rewritten only after every wave passed the 2nd barrier
        // (all reads done); part[] rewritten only after the 1st barrier of the
        // next step, which activation threads reach after consuming part[]. safe.
    }
}

// ---------------------------------------------------------------- fused scorer
__global__ __launch_bounds__(256) void scores_kernel(
    const float* __restrict__ ab, const float* __restrict__ w2,
    const float* __restrict__ b2, float* __restrict__ out)
{
    __shared__ float a_s[16 * 132];
    __shared__ float b_s[16 * 132];
    __shared__ float w_s[128];
    const int tx = threadIdx.x, ty = threadIdx.y;
    const int tid = ty * 16 + tx;
    const int n0 = blockIdx.y * 16, d0 = blockIdx.x * 16;
    float acc = 0.f;
    for (int kc = 0; kc < 1600; kc += 128) {
        for (int i = tid; i < 16 * 128; i += 256) {
            int r = i >> 7, c = i & 127;
            a_s[r * 132 + c] = ab[(size_t)(n0 + r) * NCOL + kc + c];
            b_s[r * 132 + c] = ab[(size_t)(d0 + r) * NCOL + 1600 + kc + c];
        }
        if (tid < 128) w_s[tid] = w2[kc + tid];
        __syncthreads();
#pragma unroll
        for (int k = 0; k < 128; k += 4) {
            float4 av = *(const float4*)&a_s[ty * 132 + k];
            float4 bv = *(const float4*)&b_s[tx * 132 + k];
            float4 wv = *(const float4*)&w_s[k];
            acc += fmaxf(av.x + bv.x, 0.f) * wv.x;
            acc += fmaxf(av.y + bv.y, 0.f) * wv.y;
            acc += fmaxf(av.z + bv.z, 0.f) * wv.z;
            acc += fmaxf(av.w + bv.w, 0.f) * wv.w;
        }
        __syncthreads();
    }
    int n = n0 + ty, d = d0 + tx;
    out[(size_t)(n + 1) * 321 + (d + 1)] = (n == d) ? 0.f : (acc + b2[0]);
}

__global__ void border_kernel(float* out) {
    int i = blockIdx.x * 256 + threadIdx.x;
    if (i < 321) {
        out[i]               = (i == 0) ? 1.f : 0.f;  // row 0
        out[(size_t)i * 321] = (i == 0) ? 1.f : 0.f;  // col 0
    }
}

// ---------------------------------------------------------------- launcher
extern "C" void kernel_launch(void* const* d_in, const int* in_sizes, int n_in,
                              void* d_out, int out_size, void* d_ws, size_t ws_size,
                              hipStream_t stream)
{
    const int*   words    = (const int*)d_in[0];
    const int*   tags     = (const int*)d_in[1];
    const float* wemb     = (const float*)d_in[3];
    const float* temb     = (const float*)d_in[4];
    const float* h0       = (const float*)d_in[5];
    const float* c0       = (const float*)d_in[6];
    const float* w_ih_l0  = (const float*)d_in[7];
    const float* w_hh_l0  = (const float*)d_in[8];
    const float* b_ih_l0  = (const float*)d_in[9];
    const float* b_hh_l0  = (const float*)d_in[10];
    const float* w_ih_l0r = (const float*)d_in[11];
    const float* w_hh_l0r = (const float*)d_in[12];
    const float* b_ih_l0r = (const float*)d_in[13];
    const float* b_hh_l0r = (const float*)d_in[14];
    const float* w_ih_l1  = (const float*)d_in[15];
    const float* w_hh_l1  = (const float*)d_in[16];
    const float* b_ih_l1  = (const float*)d_in[17];
    const float* b_hh_l1  = (const float*)d_in[18];
    const float* w_ih_l1r = (const float*)d_in[19];
    const float* w_hh_l1r = (const float*)d_in[20];
    const float* b_ih_l1r = (const float*)d_in[21];
    const float* b_hh_l1r = (const float*)d_in[22];
    const float* mlp_w1   = (const float*)d_in[23];
    const float* mlp_b1   = (const float*)d_in[24];
    const float* mlp_w2   = (const float*)d_in[25];
    const float* mlp_b2   = (const float*)d_in[26];
    float* out = (float*)d_out;

    float* ws     = (float*)d_ws;
    float* x      = ws;                 // 320*400   = 128000
    float* out0   = ws + 128000;        // 320*800   = 256000
    float* out1   = ws + 384000;        // 320*800   = 256000
    float* gates  = ws + 640000;        // 320*3200  = 1024000 (reused: g0, g1, ab)
    float* biasL0 = ws + 1664000;       // 3200
    float* biasL1 = ws + 1667200;       // 3200
    float* biasAB = ws + 1670400;       // 3200

    // sentinel-fill the recurrent h-history buffers (data doubles as ready flag)
    hipMemsetAsync(out0, 0xFF, (size_t)2 * 256000 * 4, stream);

    embed_kernel<<<500, 256, 0, stream>>>(words, tags, wemb, temb, x);
    bias_kernel<<<13, 256, 0, stream>>>(b_ih_l0, b_hh_l0, b_ih_l0r, b_hh_l0r,
                                        b_ih_l1, b_hh_l1, b_ih_l1r, b_hh_l1r,
                                        mlp_b1, biasL0, biasL1, biasAB);

    dim3 gdim(50, 5);
    gemm_bias<<<gdim, 256, 0, stream>>>(x, 400, 400, w_ih_l0, w_ih_l0r, 400,
                                        biasL0, gates);
    lstm_layer<<<2 * GDW, 512, 0, stream>>>(gates, w_hh_l0, w_hh_l0r,
                                            h0, h0 + 400, c0, c0 + 400, out0);
    gemm_bias<<<gdim, 256, 0, stream>>>(out0, 800, 800, w_ih_l1, w_ih_l1r, 800,
                                        biasL1, gates);
    lstm_layer<<<2 * GDW, 512, 0, stream>>>(gates, w_hh_l1, w_hh_l1r,
                                            h0 + 800, h0 + 1200, c0 + 800, c0 + 1200,
                                            out1);
    gemm_bias<<<gdim, 256, 0, stream>>>(out1, 800, 800, mlp_w1, mlp_w1 + 800, 1600,
                                        biasAB, gates);

    dim3 sgrid(20, 20), sblock(16, 16);
    scores_kernel<<<sgrid, sblock, 0, stream>>>(gates, mlp_w2, mlp_b2, out);
    border_kernel<<<2, 256, 0, stream>>>(out);
}